// Round 16
// baseline (129.131 us; speedup 1.0000x reference)
//
#include <hip/hip_runtime.h>
#include <math.h>

#define NB   4
#define SLQ  2048
#define SLK  2048
#define DIM  512
#define NH   8
#define HD   64          // head dim
#define NROWS (NB * SLQ) // 8192
#define NT   (SLK / 64)  // 32 KV tiles

typedef __attribute__((ext_vector_type(8)))  __bf16 bf16x8;
typedef __attribute__((ext_vector_type(4)))  __bf16 bf16x4;
typedef __attribute__((ext_vector_type(2)))  __bf16 bf16x2;
typedef __attribute__((ext_vector_type(4)))  float  f32x4;
typedef __attribute__((ext_vector_type(16))) float  f32x16;
typedef __attribute__((ext_vector_type(4)))  unsigned int u32x4;

// async global->LDS, 16B per lane: dest = lds_base + lane*16 (HW-defined)
typedef const __attribute__((address_space(1))) void* as1_cptr;
typedef __attribute__((address_space(3))) void*       as3_ptr;
__device__ __forceinline__ void async_ld16(const void* g, void* s) {
    __builtin_amdgcn_global_load_lds((as1_cptr)g, (as3_ptr)s, 16, 0, 0);
}

// ---------------------------------------------------------------------------
// Weight transpose + fp32->bf16: Wt[512*m + n][k] = W_m[k][n]  (m = 0..3)
// z-slice m==4: msentg[b*SLK + k] = pad_mask ? 0 : -1e30  (bf16)
// ---------------------------------------------------------------------------
__global__ __launch_bounds__(256)
void transpose_w_kernel(const float* __restrict__ Wq, const float* __restrict__ Wk,
                        const float* __restrict__ Wv, const float* __restrict__ Wo,
                        const int* __restrict__ maskp,
                        __bf16* __restrict__ Wt, __bf16* __restrict__ msentg) {
    const int m = blockIdx.z;
    const int t = threadIdx.x;
    if (m == 4) {
        const int idx = (blockIdx.y * 16 + blockIdx.x) * 256 + t;
        if (idx < NB * SLK)
            msentg[idx] = maskp[idx] ? (__bf16)0.f : (__bf16)(-1e30f);
        return;
    }
    __shared__ float Ls[32][33];
    const float* W = (m == 0) ? Wq : (m == 1) ? Wk : (m == 2) ? Wv : Wo;
    const int k0 = blockIdx.y * 32, n0 = blockIdx.x * 32;
    const int r  = t >> 3, c = (t & 7) * 4;

    const float4 v = *reinterpret_cast<const float4*>(&W[(size_t)(k0 + r) * DIM + n0 + c]);
    Ls[r][c + 0] = v.x; Ls[r][c + 1] = v.y; Ls[r][c + 2] = v.z; Ls[r][c + 3] = v.w;
    __syncthreads();

    const int n = t >> 3, k = (t & 7) * 4;
    bf16x4 o;
    o[0] = (__bf16)Ls[k + 0][n];
    o[1] = (__bf16)Ls[k + 1][n];
    o[2] = (__bf16)Ls[k + 2][n];
    o[3] = (__bf16)Ls[k + 3][n];
    *reinterpret_cast<bf16x4*>(&Wt[(size_t)(512 * m + n0 + n) * DIM + k0 + k]) = o;
}

// ---------------------------------------------------------------------------
// Fused projection GEMM, BN=128, pipelined, XCD-chunked swizzle
// (byte-identical to round 15).
// ---------------------------------------------------------------------------
__global__ __launch_bounds__(256)
void proj_mfma_kernel(const float* __restrict__ Qp, const float* __restrict__ Kp,
                      const __bf16* __restrict__ Wt,
                      const float* __restrict__ bq, const float* __restrict__ bk,
                      const float* __restrict__ bv,
                      __bf16* __restrict__ Qh, __bf16* __restrict__ Kh,
                      __bf16* __restrict__ VhT) {
    __shared__ __bf16 As[2][128][64];
    __shared__ __bf16 Bs[2][128][64];

    const int pos  = blockIdx.x;
    const int orig = (pos & 7) * 96 + (pos >> 3);   // 768 = 8*96: bijective
    const int by   = orig / 12;
    const int bx   = orig % 12;
    const int mode = bx >> 2;        // 0 Q / 1 K / 2 V
    const int cb   = bx & 3;
    const float*  Ag = (mode == 0) ? Qp : Kp;
    const __bf16* Bt = Wt + (size_t)(mode * 512) * DIM;
    const float*  biasp = ((mode == 0) ? bq : (mode == 1) ? bk : bv) + cb * 128;
    const int col0 = cb * 128;

    const int t  = threadIdx.x;
    const int w  = t >> 6, l = t & 63, lg = l >> 4, lc = l & 15;
    const int wr = w >> 1, wc = w & 1;
    const int row0 = by * 128;

    float biasr[4];
    #pragma unroll
    for (int nj = 0; nj < 4; ++nj) biasr[nj] = biasp[wc * 64 + nj * 16 + lc];
    asm volatile("s_waitcnt vmcnt(0)" ::: "memory");

    const int sr   = t >> 3;
    const int sc8  = t & 7;
    const int swA  = (sc8 ^ (sr & 7)) * 8;
    const int srow = l >> 3;
    const int schk = (l & 7) ^ srow;
    const int x7   = lc & 7;

    f32x4 acc[4][4];
    #pragma unroll
    for (int mi = 0; mi < 4; ++mi)
        #pragma unroll
        for (int nj = 0; nj < 4; ++nj) acc[mi][nj] = f32x4{0.f, 0.f, 0.f, 0.f};

    float4 areg[4][2];

#define PROJ_CF asm volatile("" ::: "memory")
#define PROJ_ISSUE_A(k0_) { _Pragma("unroll") for (int i = 0; i < 4; ++i) {    \
        const float* ap = Ag + (size_t)(row0 + i * 32 + sr) * DIM + (k0_) + sc8 * 8; \
        areg[i][0] = *reinterpret_cast<const float4*>(ap);                     \
        areg[i][1] = *reinterpret_cast<const float4*>(ap + 4); } PROJ_CF; }
#define PROJ_CVT(nb_) { _Pragma("unroll") for (int i = 0; i < 4; ++i) {        \
        bf16x8 hv;                                                             \
        hv[0] = (__bf16)areg[i][0].x; hv[1] = (__bf16)areg[i][0].y;            \
        hv[2] = (__bf16)areg[i][0].z; hv[3] = (__bf16)areg[i][0].w;            \
        hv[4] = (__bf16)areg[i][1].x; hv[5] = (__bf16)areg[i][1].y;            \
        hv[6] = (__bf16)areg[i][1].z; hv[7] = (__bf16)areg[i][1].w;            \
        *reinterpret_cast<bf16x8*>(&As[nb_][i * 32 + sr][swA]) = hv; } }
#define PROJ_STAGE_B(nb_, k0_) { _Pragma("unroll") for (int i = 0; i < 4; ++i) { \
        const int rb = w * 32 + i * 8;                                         \
        async_ld16(Bt + (size_t)(col0 + rb + srow) * DIM + (k0_) + schk * 8,   \
                   &Bs[nb_][rb][0]); } PROJ_CF; }

    PROJ_ISSUE_A(0);
    asm volatile("s_waitcnt vmcnt(0)" ::: "memory");
    PROJ_CVT(0);
    PROJ_STAGE_B(0, 0);
    PROJ_ISSUE_A(64);
    asm volatile("s_waitcnt vmcnt(8)" ::: "memory");
    asm volatile("s_waitcnt lgkmcnt(0)" ::: "memory");
    __builtin_amdgcn_s_barrier();

    for (int kt = 0; kt < 8; ++kt) {
        const int cur = kt & 1;
        if (kt + 1 < 8) PROJ_STAGE_B((kt + 1) & 1, (kt + 1) * 64);

        #pragma unroll
        for (int ks = 0; ks < 2; ++ks) {
            bf16x8 af[4], bfv[4];
            #pragma unroll
            for (int mi = 0; mi < 4; ++mi)
                af[mi] = *reinterpret_cast<const bf16x8*>(
                    &As[cur][wr * 64 + mi * 16 + lc][((ks * 4 + lg) ^ x7) << 3]);
            #pragma unroll
            for (int nj = 0; nj < 4; ++nj)
                bfv[nj] = *reinterpret_cast<const bf16x8*>(
                    &Bs[cur][wc * 64 + nj * 16 + lc][((ks * 4 + lg) ^ x7) << 3]);
            #pragma unroll
            for (int mi = 0; mi < 4; ++mi)
                #pragma unroll
                for (int nj = 0; nj < 4; ++nj)
                    acc[mi][nj] = __builtin_amdgcn_mfma_f32_16x16x32_bf16(
                        af[mi], bfv[nj], acc[mi][nj], 0, 0, 0);
        }

        if (kt + 1 < 8) {
            asm volatile("s_waitcnt vmcnt(4)" ::: "memory");
            PROJ_CVT((kt + 1) & 1);
            if (kt + 2 < 8) {
                PROJ_ISSUE_A((kt + 2) * 64);
                asm volatile("s_waitcnt vmcnt(8)" ::: "memory");
            } else {
                asm volatile("s_waitcnt vmcnt(0)" ::: "memory");
            }
            asm volatile("s_waitcnt lgkmcnt(0)" ::: "memory");
            __builtin_amdgcn_s_barrier();
        }
    }

    #pragma unroll
    for (int mi = 0; mi < 4; ++mi) {
        #pragma unroll
        for (int nj = 0; nj < 4; ++nj) {
            const int cl  = wc * 64 + nj * 16 + lc;
            const float bb = biasr[nj];
            if (mode == 2) {
                const int dcol = col0 + cl;
                const int hh = dcol >> 6, dd = dcol & 63;
                const int row = row0 + wr * 64 + mi * 16 + lg * 4;
                const int bi  = row >> 11, key = row & 2047;
                bf16x4 pk;
                #pragma unroll
                for (int r = 0; r < 4; ++r) pk[r] = (__bf16)(acc[mi][nj][r] + bb);
                *reinterpret_cast<bf16x4*>(
                    &VhT[((size_t)(bi * NH + hh) * HD + dd) * SLK + key]) = pk;
            } else {
                __bf16* out = (mode == 0) ? Qh : Kh;
                #pragma unroll
                for (int r = 0; r < 4; ++r) {
                    const int row = row0 + wr * 64 + mi * 16 + lg * 4 + r;
                    out[(size_t)row * DIM + col0 + cl] = (__bf16)(acc[mi][nj][r] + bb);
                }
            }
        }
    }
}

// ---------------------------------------------------------------------------
// FFN GEMM (byte-identical to round 15).
// ---------------------------------------------------------------------------
__global__ __launch_bounds__(256)
void ffn_mfma_kernel(const __bf16* __restrict__ A, const __bf16* __restrict__ Bt,
                     const float* __restrict__ bias, __bf16* __restrict__ outv) {
    __shared__ __bf16 As[128][72];
    __shared__ __bf16 Bs[64][72];

    const int pos  = blockIdx.x;
    const int orig = (pos & 7) * 64 + (pos >> 3);   // 512 = 8*64: bijective
    const int by   = orig >> 3;
    const int bxc  = orig & 7;

    const int t  = threadIdx.x;
    const int w  = t >> 6, l = t & 63, lg = l >> 4, lc = l & 15;
    const int wr = w >> 1, wc = w & 1;
    const int row0 = by * 128, col0 = bxc * 64;

    f32x4 acc[4][2];
    #pragma unroll
    for (int mi = 0; mi < 4; ++mi)
        #pragma unroll
        for (int nj = 0; nj < 2; ++nj) acc[mi][nj] = f32x4{0.f, 0.f, 0.f, 0.f};

    const int sr = t >> 3, sc = (t & 7) * 8;

    for (int k0 = 0; k0 < DIM; k0 += 64) {
        __syncthreads();
        #pragma unroll
        for (int i = 0; i < 4; ++i) {
            const int r = i * 32 + sr;
            *reinterpret_cast<bf16x8*>(&As[r][sc]) =
                *reinterpret_cast<const bf16x8*>(&A[(size_t)(row0 + r) * DIM + k0 + sc]);
        }
        #pragma unroll
        for (int i = 0; i < 2; ++i) {
            const int n = i * 32 + sr;
            *reinterpret_cast<bf16x8*>(&Bs[n][sc]) =
                *reinterpret_cast<const bf16x8*>(&Bt[(size_t)(col0 + n) * DIM + k0 + sc]);
        }
        __syncthreads();

        #pragma unroll
        for (int ks = 0; ks < 2; ++ks) {
            bf16x8 af[4], bfv[2];
            #pragma unroll
            for (int mi = 0; mi < 4; ++mi)
                af[mi] = *reinterpret_cast<const bf16x8*>(
                    &As[wr * 64 + mi * 16 + lc][ks * 32 + lg * 8]);
            #pragma unroll
            for (int nj = 0; nj < 2; ++nj)
                bfv[nj] = *reinterpret_cast<const bf16x8*>(
                    &Bs[wc * 32 + nj * 16 + lc][ks * 32 + lg * 8]);
            #pragma unroll
            for (int mi = 0; mi < 4; ++mi)
                #pragma unroll
                for (int nj = 0; nj < 2; ++nj)
                    acc[mi][nj] = __builtin_amdgcn_mfma_f32_16x16x32_bf16(
                        af[mi], bfv[nj], acc[mi][nj], 0, 0, 0);
        }
    }

    #pragma unroll
    for (int mi = 0; mi < 4; ++mi) {
        #pragma unroll
        for (int nj = 0; nj < 2; ++nj) {
            const int cl  = wc * 32 + nj * 16 + lc;
            const int col = col0 + cl;
            #pragma unroll
            for (int r = 0; r < 4; ++r) {
                const int row = row0 + wr * 64 + mi * 16 + lg * 4 + r;
                const float vv = acc[mi][nj][r] + bias[col];
                outv[(size_t)row * DIM + col] =
                    (__bf16)((float)A[(size_t)row * DIM + col] + fmaxf(vv, 0.f));
            }
        }
    }
}

// ---------------------------------------------------------------------------
// bf16 MFMA flash attention — 64 q-rows/block, 2 waves (128 thr), grid 1024.
// 2-buffer K/V (depth-1 prefetch: stage(t+1) issued right after the barrier,
// waited one full compute-phase later -> latency hidden), raw s_barrier,
// msent in bf16 (4 KB). LDS 36.3 KB -> 4 blocks/CU (4 independent pipelines,
// 2-wave barrier granularity). Epilogue adds the Q residual (per-head 1:1
// column slice) so LN1 needs no separate fp32 Y read.
// ---------------------------------------------------------------------------
__global__ __launch_bounds__(128)
void attn_mfma_kernel(const __bf16* __restrict__ Qh, const __bf16* __restrict__ Kh,
                      const __bf16* __restrict__ VhT, const __bf16* __restrict__ msentg,
                      const float* __restrict__ Qres, __bf16* __restrict__ Oa) {
    const int pos  = blockIdx.x;
    const int orig = (pos & 7) * 128 + (pos >> 3);   // 1024 = 8*128: bijective
    const int qb = orig & 31;          // 32 q-tiles of 64 rows
    const int h  = (orig >> 5) & 7;
    const int b  = orig >> 8;

    const int tid = threadIdx.x;       // 0..127
    const int w   = tid >> 6;          // wave 0..1
    const int l   = tid & 63;
    const int ql  = l & 31;
    const int hi  = l >> 5;
    const int x7  = ql & 7;

    __shared__ __bf16 Ks[2][64][64];   // [key][d], swizzled content (16 KB)
    __shared__ __bf16 Vt[2][64][64];   // [d][key], swizzled content (16 KB)
    __shared__ __bf16 msent[SLK];      // additive sentinels, bf16 (4 KB)
    __shared__ float  linv[2][32];

    {
        const __bf16* mb = msentg + b * SLK;
        *reinterpret_cast<bf16x8*>(&msent[tid * 16]) =
            *reinterpret_cast<const bf16x8*>(&mb[tid * 16]);
        *reinterpret_cast<bf16x8*>(&msent[tid * 16 + 8]) =
            *reinterpret_cast<const bf16x8*>(&mb[tid * 16 + 8]);
    }

    const int q0 = qb * 64 + w * 32;   // wave's 32 q rows
    bf16x8 qf[4];
    {
        const __bf16* qrow = Qh + (size_t)(b * SLQ + q0 + ql) * DIM + h * HD + hi * 8;
        #pragma unroll
        for (int c = 0; c < 4; ++c)
            qf[c] = *reinterpret_cast<const bf16x8*>(qrow + c * 16);
    }

    const __bf16* kbase = Kh  + (size_t)b * SLK * DIM + h * HD;
    const __bf16* vbase = VhT + (size_t)(b * NH + h) * HD * SLK;

    const int srow = l >> 3;
    const int schk = (l & 7) ^ srow;

    auto STAGE = [&](int nb_, int k0_) {
        #pragma unroll
        for (int i = 0; i < 4; ++i) {
            const int rb = w * 32 + i * 8;   // wave-uniform, multiple of 8
            async_ld16(kbase + (size_t)(k0_ + rb + srow) * DIM + schk * 8,
                       &Ks[nb_][rb][0]);
            async_ld16(vbase + (size_t)(rb + srow) * SLK + k0_ + schk * 8,
                       &Vt[nb_][rb][0]);
        }
    };

    f32x16 oacc[2];
    #pragma unroll
    for (int i = 0; i < 16; ++i) { oacc[0][i] = 0.f; oacc[1][i] = 0.f; }
    float l_part = 0.f;
    const float scale2 = 0.06377551f;          // (1/sqrt(512)) * log2(e)

    STAGE(0, 0);
    asm volatile("s_waitcnt lgkmcnt(0)" ::: "memory");   // own msent writes done

    for (int t = 0; t < NT; ++t) {
        asm volatile("s_waitcnt vmcnt(0)" ::: "memory"); // own stage(t) landed
        __builtin_amdgcn_s_barrier();                    // all waves' stage(t) in
        if (t + 1 < NT) STAGE((t + 1) & 1, (t + 1) * 64);

        const int k0 = t * 64;
        const __bf16* KsC = &Ks[t & 1][0][0];
        const __bf16* VtC = &Vt[t & 1][0][0];

        // ---- S^T = K . Q^T  (8 MFMAs) ----
        f32x16 sacc[2];
        #pragma unroll
        for (int i = 0; i < 16; ++i) { sacc[0][i] = 0.f; sacc[1][i] = 0.f; }
        __builtin_amdgcn_s_setprio(1);
        #pragma unroll
        for (int kb = 0; kb < 2; ++kb) {
            #pragma unroll
            for (int c = 0; c < 4; ++c) {
                const bf16x8 kf = *reinterpret_cast<const bf16x8*>(
                    &KsC[(kb * 32 + ql) * 64 + (((2 * c + hi) ^ x7) << 3)]);
                sacc[kb] = __builtin_amdgcn_mfma_f32_32x32x16_bf16(
                    kf, qf[c], sacc[kb], 0, 0, 0);
            }
        }
        __builtin_amdgcn_s_setprio(0);

        // ---- fixed-shift softmax + pack to bf16 pairs ----
        unsigned int P2[2][8];
        #pragma unroll
        for (int kb = 0; kb < 2; ++kb) {
            #pragma unroll
            for (int m = 0; m < 4; ++m) {
                const bf16x4 tmb = *reinterpret_cast<const bf16x4*>(
                    &msent[k0 + kb * 32 + 8 * m + 4 * hi]);
                float p[4];
                #pragma unroll
                for (int j = 0; j < 4; ++j) {
                    p[j] = __builtin_amdgcn_exp2f(
                        fmaf(sacc[kb][4 * m + j], scale2, (float)tmb[j]));
                    l_part += p[j];
                }
                bf16x2 w0, w1;
                w0[0] = (__bf16)p[0]; w0[1] = (__bf16)p[1];
                w1[0] = (__bf16)p[2]; w1[1] = (__bf16)p[3];
                P2[kb][2 * m]     = __builtin_bit_cast(unsigned int, w0);
                P2[kb][2 * m + 1] = __builtin_bit_cast(unsigned int, w1);
            }
        }

        // ---- permlane32_swap: build PV A-frags in place ----
        #pragma unroll
        for (int kb = 0; kb < 2; ++kb) {
            #pragma unroll
            for (int cc = 0; cc < 2; ++cc) {
                asm volatile("v_permlane32_swap_b32 %0, %1"
                             : "+v"(P2[kb][4 * cc + 0]), "+v"(P2[kb][4 * cc + 2]));
                asm volatile("v_permlane32_swap_b32 %0, %1"
                             : "+v"(P2[kb][4 * cc + 1]), "+v"(P2[kb][4 * cc + 3]));
            }
        }
        bf16x8 pfrag[4];
        #pragma unroll
        for (int c = 0; c < 4; ++c) {
            const int kb = c >> 1, cc = c & 1;
            u32x4 fw;
            fw.x = P2[kb][4 * cc + 0]; fw.y = P2[kb][4 * cc + 1];
            fw.z = P2[kb][4 * cc + 2]; fw.w = P2[kb][4 * cc + 3];
            pfrag[c] = __builtin_bit_cast(bf16x8, fw);
        }

        // ---- O += P . V  (8 MFMAs) ----
        __builtin_amdgcn_s_setprio(1);
        #pragma unroll
        for (int db = 0; db < 2; ++db) {
            #pragma unroll
            for (int c = 0; c < 4; ++c) {
                const bf16x8 vf = *reinterpret_cast<const bf16x8*>(
                    &VtC[(db * 32 + ql) * 64 + (((2 * c + hi) ^ x7) << 3)]);
                oacc[db] = __builtin_amdgcn_mfma_f32_32x32x16_bf16(
                    pfrag[c], vf, oacc[db], 0, 0, 0);
            }
        }
        __builtin_amdgcn_s_setprio(0);
    }

    // ---- epilogue: l reduction + normalize + Q residual + bf16 store ----
    const float lsum = l_part + __shfl_xor(l_part, 32, 64);
    if (hi == 0) linv[w][ql] = (lsum > 0.f) ? 1.f / lsum : 0.f;  // all-masked -> 0
    #pragma unroll
    for (int db = 0; db < 2; ++db) {
        #pragma unroll
        for (int m = 0; m < 4; ++m) {
            const f32x4 iv = *reinterpret_cast<const f32x4*>(&linv[w][8 * m + 4 * hi]);
            #pragma unroll
            for (int j = 0; j < 4; ++j) {
                const int qr = 8 * m + 4 * hi + j;
                const size_t idx = (size_t)(b * SLQ + q0 + qr) * DIM + h * HD + db * 32 + ql;
                Oa[idx] = (__bf16)(oacc[db][4 * m + j] * iv[j] + Qres[idx]);
            }
        }
    }
}

// ---------------------------------------------------------------------------
// Wave helper + LayerNorms
// ---------------------------------------------------------------------------
__device__ __forceinline__ float wave_sum(float v) {
    #pragma unroll
    for (int off = 32; off > 0; off >>= 1) v += __shfl_xor(v, off, 64);
    return v;
}

// LN1: out(bf16) = LN( X(bf16, already attn-out + Q residual) )
__global__ __launch_bounds__(256)
void ln1_kernel(const __bf16* X, const float* g, const float* bta, __bf16* out) {
    const int w    = threadIdx.x >> 6;
    const int lane = threadIdx.x & 63;
    const int row  = blockIdx.x * 4 + w;
    const size_t base = (size_t)row * DIM + lane * 8;

    const bf16x8 xv = *reinterpret_cast<const bf16x8*>(&X[base]);
    float v[8];
    #pragma unroll
    for (int i = 0; i < 8; ++i) v[i] = (float)xv[i];

    float s = 0.f, ss = 0.f;
    #pragma unroll
    for (int i = 0; i < 8; ++i) { s += v[i]; ss += v[i] * v[i]; }
    s  = wave_sum(s);
    ss = wave_sum(ss);
    const float mean = s * (1.f / DIM);
    const float var  = ss * (1.f / DIM) - mean * mean;
    const float rstd = rsqrtf(var + 1e-5f);

    const float4 g0 = *reinterpret_cast<const float4*>(&g[lane * 8]);
    const float4 g1 = *reinterpret_cast<const float4*>(&g[lane * 8 + 4]);
    const float4 b0 = *reinterpret_cast<const float4*>(&bta[lane * 8]);
    const float4 b1 = *reinterpret_cast<const float4*>(&bta[lane * 8 + 4]);
    float gg[8] = {g0.x, g0.y, g0.z, g0.w, g1.x, g1.y, g1.z, g1.w};
    float bb[8] = {b0.x, b0.y, b0.z, b0.w, b1.x, b1.y, b1.z, b1.w};

    bf16x8 o;
    #pragma unroll
    for (int i = 0; i < 8; ++i)
        o[i] = (__bf16)((v[i] - mean) * rstd * gg[i] + bb[i]);
    *reinterpret_cast<bf16x8*>(&out[base]) = o;
}

// LN2: out(fp32) = LN( X(bf16) )
__global__ __launch_bounds__(256)
void ln2_kernel(const __bf16* X, const float* g, const float* bta, float* out) {
    const int w    = threadIdx.x >> 6;
    const int lane = threadIdx.x & 63;
    const int row  = blockIdx.x * 4 + w;
    const size_t base = (size_t)row * DIM + lane * 8;

    const bf16x8 xv = *reinterpret_cast<const bf16x8*>(&X[base]);
    float v[8];
    #pragma unroll
    for (int i = 0; i < 8; ++i) v[i] = (float)xv[i];

    float s = 0.f, ss = 0.f;
    #pragma unroll
    for (int i = 0; i < 8; ++i) { s += v[i]; ss += v[i] * v[i]; }
    s  = wave_sum(s);
    ss = wave_sum(ss);
    const float mean = s * (1.f / DIM);
    const float var  = ss * (1.f / DIM) - mean * mean;
    const float rstd = rsqrtf(var + 1e-5f);

    const float4 g0 = *reinterpret_cast<const float4*>(&g[lane * 8]);
    const float4 g1 = *reinterpret_cast<const float4*>(&g[lane * 8 + 4]);
    const float4 b0 = *reinterpret_cast<const float4*>(&bta[lane * 8]);
    const float4 b1 = *reinterpret_cast<const float4*>(&bta[lane * 8 + 4]);
    float gg[8] = {g0.x, g0.y, g0.z, g0.w, g1.x, g1.y, g1.z, g1.w};
    float bb[8] = {b0.x, b0.y, b0.z, b0.w, b1.x, b1.y, b1.z, b1.w};

    float4 o0, o1;
    o0.x = (v[0] - mean) * rstd * gg[0] + bb[0];
    o0.y = (v[1] - mean) * rstd * gg[1] + bb[1];
    o0.z = (v[2] - mean) * rstd * gg[2] + bb[2];
    o0.w = (v[3] - mean) * rstd * gg[3] + bb[3];
    o1.x = (v[4] - mean) * rstd * gg[4] + bb[4];
    o1.y = (v[5] - mean) * rstd * gg[5] + bb[5];
    o1.z = (v[6] - mean) * rstd * gg[6] + bb[6];
    o1.w = (v[7] - mean) * rstd * gg[7] + bb[7];
    *reinterpret_cast<float4*>(&out[base])     = o0;
    *reinterpret_cast<float4*>(&out[base + 4]) = o1;
}

// ---------------------------------------------------------------------------
// Workspace layout (42.03 MB; all live ranges DISJOINT):
//   Qh  bf16 @ 0  .. 8 MB    (proj -> attn)
//   Kh  bf16 @ 8  .. 16 MB   (proj -> attn)
//   VhT bf16 @ 16 .. 24 MB   (proj -> attn)
//   Wt  bf16 @ 24 .. 26 MB   (transpose -> GEMMs)
//   Oa  bf16 @ 26 .. 34 MB   (attn(+Q) -> ln1)
//   H1  bf16 @ 34 .. 42 MB   (ln1 -> ffn)
//   msentg bf16 @ 42 MB (16 KB)
//   R2  bf16 @ 0 .. 8 MB     (ffn -> ln2)  [over DEAD Qh]
// d_out written only by LN2 (final).
// ---------------------------------------------------------------------------
extern "C" void kernel_launch(void* const* d_in, const int* in_sizes, int n_in,
                              void* d_out, int out_size, void* d_ws, size_t ws_size,
                              hipStream_t stream) {
    const float* Q     = (const float*)d_in[0];
    const float* K     = (const float*)d_in[1];
    const int*   maskp = (const int*)  d_in[2];
    const float* Wq    = (const float*)d_in[3];
    const float* bq    = (const float*)d_in[4];
    const float* Wk    = (const float*)d_in[5];
    const float* bk    = (const float*)d_in[6];
    const float* Wv    = (const float*)d_in[7];
    const float* bv    = (const float*)d_in[8];
    const float* Wo    = (const float*)d_in[9];
    const float* bo    = (const float*)d_in[10];
    const float* g0    = (const float*)d_in[11];
    const float* b0    = (const float*)d_in[12];
    const float* g1    = (const float*)d_in[13];
    const float* b1    = (const float*)d_in[14];

    float* out = (float*)d_out;
    char*  ws  = (char*)d_ws;
    __bf16* Qh     = (__bf16*)ws;
    __bf16* Kh     = (__bf16*)(ws + (8u  << 20));
    __bf16* VhT    = (__bf16*)(ws + (16u << 20));
    __bf16* Wt     = (__bf16*)(ws + (24u << 20));
    __bf16* Oa     = (__bf16*)(ws + (26u << 20));
    __bf16* H1     = (__bf16*)(ws + (34u << 20));
    __bf16* msentg = (__bf16*)(ws + (42u << 20));
    __bf16* R2     = (__bf16*)ws;

    transpose_w_kernel<<<dim3(16, 16, 5), 256, 0, stream>>>(
        Wq, Wk, Wv, Wo, maskp, Wt, msentg);

    proj_mfma_kernel<<<dim3(768), 256, 0, stream>>>(
        Q, K, Wt, bq, bk, bv, Qh, Kh, VhT);

    attn_mfma_kernel<<<dim3(1024), 128, 0, stream>>>(
        Qh, Kh, VhT, msentg, Q, Oa);

    ln1_kernel<<<NROWS / 4, 256, 0, stream>>>(Oa, g0, b0, H1);

    ffn_mfma_kernel<<<dim3(512), 256, 0, stream>>>(
        H1, Wt + (size_t)1536 * DIM, bo, R2);

    ln2_kernel<<<NROWS / 4, 256, 0, stream>>>(R2, g1, b1, out);
}

// Round 17
// 125.366 us; speedup vs baseline: 1.0300x; 1.0300x over previous
//
#include <hip/hip_runtime.h>
#include <math.h>

#define NB   4
#define SLQ  2048
#define SLK  2048
#define DIM  512
#define NH   8
#define HD   64          // head dim
#define NROWS (NB * SLQ) // 8192
#define NT   (SLK / 64)  // 32 KV tiles

typedef __attribute__((ext_vector_type(8)))  __bf16 bf16x8;
typedef __attribute__((ext_vector_type(4)))  __bf16 bf16x4;
typedef __attribute__((ext_vector_type(2)))  __bf16 bf16x2;
typedef __attribute__((ext_vector_type(4)))  float  f32x4;
typedef __attribute__((ext_vector_type(16))) float  f32x16;
typedef __attribute__((ext_vector_type(4)))  unsigned int u32x4;

// async global->LDS, 16B per lane: dest = lds_base + lane*16 (HW-defined)
typedef const __attribute__((address_space(1))) void* as1_cptr;
typedef __attribute__((address_space(3))) void*       as3_ptr;
__device__ __forceinline__ void async_ld16(const void* g, void* s) {
    __builtin_amdgcn_global_load_lds((as1_cptr)g, (as3_ptr)s, 16, 0, 0);
}

// ---------------------------------------------------------------------------
// Weight transpose + fp32->bf16: Wt[512*m + n][k] = W_m[k][n]  (m = 0..3)
// z-slice m==4: msentg[b*SLK + k] = pad_mask ? 0 : -1e30 (fp32)
// ---------------------------------------------------------------------------
__global__ __launch_bounds__(256)
void transpose_w_kernel(const float* __restrict__ Wq, const float* __restrict__ Wk,
                        const float* __restrict__ Wv, const float* __restrict__ Wo,
                        const int* __restrict__ maskp,
                        __bf16* __restrict__ Wt, float* __restrict__ msentg) {
    const int m = blockIdx.z;
    const int t = threadIdx.x;
    if (m == 4) {
        const int idx = (blockIdx.y * 16 + blockIdx.x) * 256 + t;
        if (idx < NB * SLK) msentg[idx] = maskp[idx] ? 0.f : -1e30f;
        return;
    }
    __shared__ float Ls[32][33];
    const float* W = (m == 0) ? Wq : (m == 1) ? Wk : (m == 2) ? Wv : Wo;
    const int k0 = blockIdx.y * 32, n0 = blockIdx.x * 32;
    const int r  = t >> 3, c = (t & 7) * 4;

    const float4 v = *reinterpret_cast<const float4*>(&W[(size_t)(k0 + r) * DIM + n0 + c]);
    Ls[r][c + 0] = v.x; Ls[r][c + 1] = v.y; Ls[r][c + 2] = v.z; Ls[r][c + 3] = v.w;
    __syncthreads();

    const int n = t >> 3, k = (t & 7) * 4;
    bf16x4 o;
    o[0] = (__bf16)Ls[k + 0][n];
    o[1] = (__bf16)Ls[k + 1][n];
    o[2] = (__bf16)Ls[k + 2][n];
    o[3] = (__bf16)Ls[k + 3][n];
    *reinterpret_cast<bf16x4*>(&Wt[(size_t)(512 * m + n0 + n) * DIM + k0 + k]) = o;
}

// ---------------------------------------------------------------------------
// Fused projection GEMM, BN=128, pipelined, XCD-chunked swizzle
// (byte-identical to round 15).
// ---------------------------------------------------------------------------
__global__ __launch_bounds__(256)
void proj_mfma_kernel(const float* __restrict__ Qp, const float* __restrict__ Kp,
                      const __bf16* __restrict__ Wt,
                      const float* __restrict__ bq, const float* __restrict__ bk,
                      const float* __restrict__ bv,
                      __bf16* __restrict__ Qh, __bf16* __restrict__ Kh,
                      __bf16* __restrict__ VhT) {
    __shared__ __bf16 As[2][128][64];
    __shared__ __bf16 Bs[2][128][64];

    const int pos  = blockIdx.x;
    const int orig = (pos & 7) * 96 + (pos >> 3);   // 768 = 8*96: bijective
    const int by   = orig / 12;
    const int bx   = orig % 12;
    const int mode = bx >> 2;        // 0 Q / 1 K / 2 V
    const int cb   = bx & 3;
    const float*  Ag = (mode == 0) ? Qp : Kp;
    const __bf16* Bt = Wt + (size_t)(mode * 512) * DIM;
    const float*  biasp = ((mode == 0) ? bq : (mode == 1) ? bk : bv) + cb * 128;
    const int col0 = cb * 128;

    const int t  = threadIdx.x;
    const int w  = t >> 6, l = t & 63, lg = l >> 4, lc = l & 15;
    const int wr = w >> 1, wc = w & 1;
    const int row0 = by * 128;

    float biasr[4];
    #pragma unroll
    for (int nj = 0; nj < 4; ++nj) biasr[nj] = biasp[wc * 64 + nj * 16 + lc];
    asm volatile("s_waitcnt vmcnt(0)" ::: "memory");

    const int sr   = t >> 3;
    const int sc8  = t & 7;
    const int swA  = (sc8 ^ (sr & 7)) * 8;
    const int srow = l >> 3;
    const int schk = (l & 7) ^ srow;
    const int x7   = lc & 7;

    f32x4 acc[4][4];
    #pragma unroll
    for (int mi = 0; mi < 4; ++mi)
        #pragma unroll
        for (int nj = 0; nj < 4; ++nj) acc[mi][nj] = f32x4{0.f, 0.f, 0.f, 0.f};

    float4 areg[4][2];

#define PROJ_CF asm volatile("" ::: "memory")
#define PROJ_ISSUE_A(k0_) { _Pragma("unroll") for (int i = 0; i < 4; ++i) {    \
        const float* ap = Ag + (size_t)(row0 + i * 32 + sr) * DIM + (k0_) + sc8 * 8; \
        areg[i][0] = *reinterpret_cast<const float4*>(ap);                     \
        areg[i][1] = *reinterpret_cast<const float4*>(ap + 4); } PROJ_CF; }
#define PROJ_CVT(nb_) { _Pragma("unroll") for (int i = 0; i < 4; ++i) {        \
        bf16x8 hv;                                                             \
        hv[0] = (__bf16)areg[i][0].x; hv[1] = (__bf16)areg[i][0].y;            \
        hv[2] = (__bf16)areg[i][0].z; hv[3] = (__bf16)areg[i][0].w;            \
        hv[4] = (__bf16)areg[i][1].x; hv[5] = (__bf16)areg[i][1].y;            \
        hv[6] = (__bf16)areg[i][1].z; hv[7] = (__bf16)areg[i][1].w;            \
        *reinterpret_cast<bf16x8*>(&As[nb_][i * 32 + sr][swA]) = hv; } }
#define PROJ_STAGE_B(nb_, k0_) { _Pragma("unroll") for (int i = 0; i < 4; ++i) { \
        const int rb = w * 32 + i * 8;                                         \
        async_ld16(Bt + (size_t)(col0 + rb + srow) * DIM + (k0_) + schk * 8,   \
                   &Bs[nb_][rb][0]); } PROJ_CF; }

    PROJ_ISSUE_A(0);
    asm volatile("s_waitcnt vmcnt(0)" ::: "memory");
    PROJ_CVT(0);
    PROJ_STAGE_B(0, 0);
    PROJ_ISSUE_A(64);
    asm volatile("s_waitcnt vmcnt(8)" ::: "memory");
    asm volatile("s_waitcnt lgkmcnt(0)" ::: "memory");
    __builtin_amdgcn_s_barrier();

    for (int kt = 0; kt < 8; ++kt) {
        const int cur = kt & 1;
        if (kt + 1 < 8) PROJ_STAGE_B((kt + 1) & 1, (kt + 1) * 64);

        #pragma unroll
        for (int ks = 0; ks < 2; ++ks) {
            bf16x8 af[4], bfv[4];
            #pragma unroll
            for (int mi = 0; mi < 4; ++mi)
                af[mi] = *reinterpret_cast<const bf16x8*>(
                    &As[cur][wr * 64 + mi * 16 + lc][((ks * 4 + lg) ^ x7) << 3]);
            #pragma unroll
            for (int nj = 0; nj < 4; ++nj)
                bfv[nj] = *reinterpret_cast<const bf16x8*>(
                    &Bs[cur][wc * 64 + nj * 16 + lc][((ks * 4 + lg) ^ x7) << 3]);
            #pragma unroll
            for (int mi = 0; mi < 4; ++mi)
                #pragma unroll
                for (int nj = 0; nj < 4; ++nj)
                    acc[mi][nj] = __builtin_amdgcn_mfma_f32_16x16x32_bf16(
                        af[mi], bfv[nj], acc[mi][nj], 0, 0, 0);
        }

        if (kt + 1 < 8) {
            asm volatile("s_waitcnt vmcnt(4)" ::: "memory");
            PROJ_CVT((kt + 1) & 1);
            if (kt + 2 < 8) {
                PROJ_ISSUE_A((kt + 2) * 64);
                asm volatile("s_waitcnt vmcnt(8)" ::: "memory");
            } else {
                asm volatile("s_waitcnt vmcnt(0)" ::: "memory");
            }
            asm volatile("s_waitcnt lgkmcnt(0)" ::: "memory");
            __builtin_amdgcn_s_barrier();
        }
    }

    #pragma unroll
    for (int mi = 0; mi < 4; ++mi) {
        #pragma unroll
        for (int nj = 0; nj < 4; ++nj) {
            const int cl  = wc * 64 + nj * 16 + lc;
            const float bb = biasr[nj];
            if (mode == 2) {
                const int dcol = col0 + cl;
                const int hh = dcol >> 6, dd = dcol & 63;
                const int row = row0 + wr * 64 + mi * 16 + lg * 4;
                const int bi  = row >> 11, key = row & 2047;
                bf16x4 pk;
                #pragma unroll
                for (int r = 0; r < 4; ++r) pk[r] = (__bf16)(acc[mi][nj][r] + bb);
                *reinterpret_cast<bf16x4*>(
                    &VhT[((size_t)(bi * NH + hh) * HD + dd) * SLK + key]) = pk;
            } else {
                __bf16* out = (mode == 0) ? Qh : Kh;
                #pragma unroll
                for (int r = 0; r < 4; ++r) {
                    const int row = row0 + wr * 64 + mi * 16 + lg * 4 + r;
                    out[(size_t)row * DIM + col0 + cl] = (__bf16)(acc[mi][nj][r] + bb);
                }
            }
        }
    }
}

// ---------------------------------------------------------------------------
// FFN GEMM (byte-identical to round 15).
// ---------------------------------------------------------------------------
__global__ __launch_bounds__(256)
void ffn_mfma_kernel(const __bf16* __restrict__ A, const __bf16* __restrict__ Bt,
                     const float* __restrict__ bias, __bf16* __restrict__ outv) {
    __shared__ __bf16 As[128][72];
    __shared__ __bf16 Bs[64][72];

    const int pos  = blockIdx.x;
    const int orig = (pos & 7) * 64 + (pos >> 3);   // 512 = 8*64: bijective
    const int by   = orig >> 3;
    const int bxc  = orig & 7;

    const int t  = threadIdx.x;
    const int w  = t >> 6, l = t & 63, lg = l >> 4, lc = l & 15;
    const int wr = w >> 1, wc = w & 1;
    const int row0 = by * 128, col0 = bxc * 64;

    f32x4 acc[4][2];
    #pragma unroll
    for (int mi = 0; mi < 4; ++mi)
        #pragma unroll
        for (int nj = 0; nj < 2; ++nj) acc[mi][nj] = f32x4{0.f, 0.f, 0.f, 0.f};

    const int sr = t >> 3, sc = (t & 7) * 8;

    for (int k0 = 0; k0 < DIM; k0 += 64) {
        __syncthreads();
        #pragma unroll
        for (int i = 0; i < 4; ++i) {
            const int r = i * 32 + sr;
            *reinterpret_cast<bf16x8*>(&As[r][sc]) =
                *reinterpret_cast<const bf16x8*>(&A[(size_t)(row0 + r) * DIM + k0 + sc]);
        }
        #pragma unroll
        for (int i = 0; i < 2; ++i) {
            const int n = i * 32 + sr;
            *reinterpret_cast<bf16x8*>(&Bs[n][sc]) =
                *reinterpret_cast<const bf16x8*>(&Bt[(size_t)(col0 + n) * DIM + k0 + sc]);
        }
        __syncthreads();

        #pragma unroll
        for (int ks = 0; ks < 2; ++ks) {
            bf16x8 af[4], bfv[2];
            #pragma unroll
            for (int mi = 0; mi < 4; ++mi)
                af[mi] = *reinterpret_cast<const bf16x8*>(
                    &As[wr * 64 + mi * 16 + lc][ks * 32 + lg * 8]);
            #pragma unroll
            for (int nj = 0; nj < 2; ++nj)
                bfv[nj] = *reinterpret_cast<const bf16x8*>(
                    &Bs[wc * 32 + nj * 16 + lc][ks * 32 + lg * 8]);
            #pragma unroll
            for (int mi = 0; mi < 4; ++mi)
                #pragma unroll
                for (int nj = 0; nj < 2; ++nj)
                    acc[mi][nj] = __builtin_amdgcn_mfma_f32_16x16x32_bf16(
                        af[mi], bfv[nj], acc[mi][nj], 0, 0, 0);
        }
    }

    #pragma unroll
    for (int mi = 0; mi < 4; ++mi) {
        #pragma unroll
        for (int nj = 0; nj < 2; ++nj) {
            const int cl  = wc * 32 + nj * 16 + lc;
            const int col = col0 + cl;
            #pragma unroll
            for (int r = 0; r < 4; ++r) {
                const int row = row0 + wr * 64 + mi * 16 + lg * 4 + r;
                const float vv = acc[mi][nj][r] + bias[col];
                outv[(size_t)row * DIM + col] =
                    (__bf16)((float)A[(size_t)row * DIM + col] + fmaxf(vv, 0.f));
            }
        }
    }
}

// ---------------------------------------------------------------------------
// bf16 MFMA flash attention — round-15 structure with pipeline deepened to
// 4 K/V LDS buffers (3 tiles in flight). Counted waits: vmcnt(16) steady
// (tiles t,t+1,t+2 in flight = 24 loads; wait leaves 16 -> tile t's 8 done),
// vmcnt(8) at t=NT-2, vmcnt(0) at t=NT-1. Raw s_barrier (no drain).
// LDS = 4*16K (K/V) + 8K (msent) + 0.5K = 72.5 KB -> 2 blocks/CU (unchanged).
// ---------------------------------------------------------------------------
__global__ __launch_bounds__(256)
void attn_mfma_kernel(const __bf16* __restrict__ Qh, const __bf16* __restrict__ Kh,
                      const __bf16* __restrict__ VhT, const float* __restrict__ msentg,
                      __bf16* __restrict__ Oa) {
    const int pos  = blockIdx.x;
    const int orig = (pos & 7) * 64 + (pos >> 3);   // 512 % 8 == 0: bijective
    const int qb = orig & 15;          // 16 q-tiles of 128 rows
    const int h  = (orig >> 4) & 7;
    const int b  = orig >> 7;

    const int tid = threadIdx.x;
    const int w   = tid >> 6;
    const int l   = tid & 63;
    const int ql  = l & 31;
    const int hi  = l >> 5;
    const int x7  = ql & 7;

    __shared__ __bf16 Ks[4][64][64];   // [key][d], swizzled content
    __shared__ __bf16 Vt[4][64][64];   // [d][key], swizzled content
    __shared__ float  msent[SLK];      // additive sentinels (8 KB)
    __shared__ float  linv[4][32];     // per-wave 1/l broadcast

    {
        const float* mb = msentg + b * SLK;
        #pragma unroll
        for (int i = 0; i < 2; ++i) {
            const int idx = (i * 256 + tid) * 4;
            *reinterpret_cast<f32x4*>(&msent[idx]) =
                *reinterpret_cast<const f32x4*>(&mb[idx]);
        }
    }

    const int q0 = qb * 128 + w * 32;  // wave's 32 q rows
    bf16x8 qf[4];
    {
        const __bf16* qrow = Qh + (size_t)(b * SLQ + q0 + ql) * DIM + h * HD + hi * 8;
        #pragma unroll
        for (int c = 0; c < 4; ++c)
            qf[c] = *reinterpret_cast<const bf16x8*>(qrow + c * 16);
    }

    const __bf16* kbase = Kh  + (size_t)b * SLK * DIM + h * HD;
    const __bf16* vbase = VhT + (size_t)(b * NH + h) * HD * SLK;

    const int srow = l >> 3;
    const int schk = (l & 7) ^ srow;

    auto STAGE = [&](int nb_, int k0_) {
        #pragma unroll
        for (int i = 0; i < 2; ++i) {
            const int rb = w * 16 + i * 8;   // wave-uniform, multiple of 8
            async_ld16(kbase + (size_t)(k0_ + rb + srow) * DIM + schk * 8,
                       &Ks[nb_][rb][0]);
            async_ld16(vbase + (size_t)(rb + srow) * SLK + k0_ + schk * 8,
                       &Vt[nb_][rb][0]);
        }
    };

    f32x16 oacc[2];
    #pragma unroll
    for (int i = 0; i < 16; ++i) { oacc[0][i] = 0.f; oacc[1][i] = 0.f; }
    float l_part = 0.f;
    const float scale2 = 0.06377551f;          // (1/sqrt(512)) * log2(e)

    STAGE(0, 0);
    STAGE(1, 64);
    STAGE(2, 128);
    asm volatile("s_waitcnt lgkmcnt(0)" ::: "memory");   // own msent writes done

    for (int t = 0; t < NT; ++t) {
        // counted wait: tile t's loads done; t+1,t+2 stay in flight (T4)
        if (t < NT - 2)       asm volatile("s_waitcnt vmcnt(16)" ::: "memory");
        else if (t == NT - 2) asm volatile("s_waitcnt vmcnt(8)"  ::: "memory");
        else                  asm volatile("s_waitcnt vmcnt(0)"  ::: "memory");
        __builtin_amdgcn_s_barrier();    // RAW barrier: no implicit drain

        if (t + 3 < NT) STAGE((t + 3) & 3, (t + 3) * 64);

        const int k0 = t * 64;
        const __bf16* KsC = &Ks[t & 3][0][0];
        const __bf16* VtC = &Vt[t & 3][0][0];

        // ---- S^T = K . Q^T  (8 MFMAs) ----
        f32x16 sacc[2];
        #pragma unroll
        for (int i = 0; i < 16; ++i) { sacc[0][i] = 0.f; sacc[1][i] = 0.f; }
        __builtin_amdgcn_s_setprio(1);
        #pragma unroll
        for (int kb = 0; kb < 2; ++kb) {
            #pragma unroll
            for (int c = 0; c < 4; ++c) {
                const bf16x8 kf = *reinterpret_cast<const bf16x8*>(
                    &KsC[(kb * 32 + ql) * 64 + (((2 * c + hi) ^ x7) << 3)]);
                sacc[kb] = __builtin_amdgcn_mfma_f32_32x32x16_bf16(
                    kf, qf[c], sacc[kb], 0, 0, 0);
            }
        }
        __builtin_amdgcn_s_setprio(0);

        // ---- fixed-shift softmax + pack to bf16 pairs ----
        unsigned int P2[2][8];
        #pragma unroll
        for (int kb = 0; kb < 2; ++kb) {
            #pragma unroll
            for (int m = 0; m < 4; ++m) {
                const f32x4 tm = *reinterpret_cast<const f32x4*>(
                    &msent[k0 + kb * 32 + 8 * m + 4 * hi]);
                float p[4];
                #pragma unroll
                for (int j = 0; j < 4; ++j) {
                    p[j] = __builtin_amdgcn_exp2f(
                        fmaf(sacc[kb][4 * m + j], scale2, tm[j]));  // masked -> 0
                    l_part += p[j];
                }
                bf16x2 w0, w1;
                w0[0] = (__bf16)p[0]; w0[1] = (__bf16)p[1];
                w1[0] = (__bf16)p[2]; w1[1] = (__bf16)p[3];
                P2[kb][2 * m]     = __builtin_bit_cast(unsigned int, w0);
                P2[kb][2 * m + 1] = __builtin_bit_cast(unsigned int, w1);
            }
        }

        // ---- permlane32_swap: build PV A-frags in place ----
        #pragma unroll
        for (int kb = 0; kb < 2; ++kb) {
            #pragma unroll
            for (int cc = 0; cc < 2; ++cc) {
                asm volatile("v_permlane32_swap_b32 %0, %1"
                             : "+v"(P2[kb][4 * cc + 0]), "+v"(P2[kb][4 * cc + 2]));
                asm volatile("v_permlane32_swap_b32 %0, %1"
                             : "+v"(P2[kb][4 * cc + 1]), "+v"(P2[kb][4 * cc + 3]));
            }
        }
        bf16x8 pfrag[4];
        #pragma unroll
        for (int c = 0; c < 4; ++c) {
            const int kb = c >> 1, cc = c & 1;
            u32x4 fw;
            fw.x = P2[kb][4 * cc + 0]; fw.y = P2[kb][4 * cc + 1];
            fw.z = P2[kb][4 * cc + 2]; fw.w = P2[kb][4 * cc + 3];
            pfrag[c] = __builtin_bit_cast(bf16x8, fw);
        }

        // ---- O += P . V  (8 MFMAs) ----
        __builtin_amdgcn_s_setprio(1);
        #pragma unroll
        for (int db = 0; db < 2; ++db) {
            #pragma unroll
            for (int c = 0; c < 4; ++c) {
                const bf16x8 vf = *reinterpret_cast<const bf16x8*>(
                    &VtC[(db * 32 + ql) * 64 + (((2 * c + hi) ^ x7) << 3)]);
                oacc[db] = __builtin_amdgcn_mfma_f32_32x32x16_bf16(
                    pfrag[c], vf, oacc[db], 0, 0, 0);
            }
        }
        __builtin_amdgcn_s_setprio(0);
    }

    // ---- epilogue: l reduction + normalize + bf16 store ----
    const float lsum = l_part + __shfl_xor(l_part, 32, 64);
    if (hi == 0) linv[w][ql] = (lsum > 0.f) ? 1.f / lsum : 0.f;  // all-masked -> 0
    #pragma unroll
    for (int db = 0; db < 2; ++db) {
        #pragma unroll
        for (int m = 0; m < 4; ++m) {
            const f32x4 iv = *reinterpret_cast<const f32x4*>(&linv[w][8 * m + 4 * hi]);
            #pragma unroll
            for (int j = 0; j < 4; ++j) {
                const int qr = 8 * m + 4 * hi + j;
                Oa[(size_t)(b * SLQ + q0 + qr) * DIM + h * HD + db * 32 + ql] =
                    (__bf16)(oacc[db][4 * m + j] * iv[j]);
            }
        }
    }
}

// ---------------------------------------------------------------------------
// Wave helper + LayerNorms (round-15 versions)
// ---------------------------------------------------------------------------
__device__ __forceinline__ float wave_sum(float v) {
    #pragma unroll
    for (int off = 32; off > 0; off >>= 1) v += __shfl_xor(v, off, 64);
    return v;
}

// LN1: out(bf16) = LN( X(bf16 attn out) + Y(fp32 residual) )
__global__ __launch_bounds__(256)
void ln1_kernel(const __bf16* X, const float* Y,
                const float* g, const float* bta, __bf16* out) {
    const int w    = threadIdx.x >> 6;
    const int lane = threadIdx.x & 63;
    const int row  = blockIdx.x * 4 + w;
    const size_t base = (size_t)row * DIM + lane * 8;

    const bf16x8 xv = *reinterpret_cast<const bf16x8*>(&X[base]);
    const float4 y0 = *reinterpret_cast<const float4*>(&Y[base]);
    const float4 y1 = *reinterpret_cast<const float4*>(&Y[base + 4]);
    float v[8];
    v[0] = (float)xv[0] + y0.x; v[1] = (float)xv[1] + y0.y;
    v[2] = (float)xv[2] + y0.z; v[3] = (float)xv[3] + y0.w;
    v[4] = (float)xv[4] + y1.x; v[5] = (float)xv[5] + y1.y;
    v[6] = (float)xv[6] + y1.z; v[7] = (float)xv[7] + y1.w;

    float s = 0.f, ss = 0.f;
    #pragma unroll
    for (int i = 0; i < 8; ++i) { s += v[i]; ss += v[i] * v[i]; }
    s  = wave_sum(s);
    ss = wave_sum(ss);
    const float mean = s * (1.f / DIM);
    const float var  = ss * (1.f / DIM) - mean * mean;
    const float rstd = rsqrtf(var + 1e-5f);

    const float4 g0 = *reinterpret_cast<const float4*>(&g[lane * 8]);
    const float4 g1 = *reinterpret_cast<const float4*>(&g[lane * 8 + 4]);
    const float4 b0 = *reinterpret_cast<const float4*>(&bta[lane * 8]);
    const float4 b1 = *reinterpret_cast<const float4*>(&bta[lane * 8 + 4]);
    float gg[8] = {g0.x, g0.y, g0.z, g0.w, g1.x, g1.y, g1.z, g1.w};
    float bb[8] = {b0.x, b0.y, b0.z, b0.w, b1.x, b1.y, b1.z, b1.w};

    bf16x8 o;
    #pragma unroll
    for (int i = 0; i < 8; ++i)
        o[i] = (__bf16)((v[i] - mean) * rstd * gg[i] + bb[i]);
    *reinterpret_cast<bf16x8*>(&out[base]) = o;
}

// LN2: out(fp32) = LN( X(bf16) )
__global__ __launch_bounds__(256)
void ln2_kernel(const __bf16* X, const float* g, const float* bta, float* out) {
    const int w    = threadIdx.x >> 6;
    const int lane = threadIdx.x & 63;
    const int row  = blockIdx.x * 4 + w;
    const size_t base = (size_t)row * DIM + lane * 8;

    const bf16x8 xv = *reinterpret_cast<const bf16x8*>(&X[base]);
    float v[8];
    #pragma unroll
    for (int i = 0; i < 8; ++i) v[i] = (float)xv[i];

    float s = 0.f, ss = 0.f;
    #pragma unroll
    for (int i = 0; i < 8; ++i) { s += v[i]; ss += v[i] * v[i]; }
    s  = wave_sum(s);
    ss = wave_sum(ss);
    const float mean = s * (1.f / DIM);
    const float var  = ss * (1.f / DIM) - mean * mean;
    const float rstd = rsqrtf(var + 1e-5f);

    const float4 g0 = *reinterpret_cast<const float4*>(&g[lane * 8]);
    const float4 g1 = *reinterpret_cast<const float4*>(&g[lane * 8 + 4]);
    const float4 b0 = *reinterpret_cast<const float4*>(&bta[lane * 8]);
    const float4 b1 = *reinterpret_cast<const float4*>(&bta[lane * 8 + 4]);
    float gg[8] = {g0.x, g0.y, g0.z, g0.w, g1.x, g1.y, g1.z, g1.w};
    float bb[8] = {b0.x, b0.y, b0.z, b0.w, b1.x, b1.y, b1.z, b1.w};

    float4 o0, o1;
    o0.x = (v[0] - mean) * rstd * gg[0] + bb[0];
    o0.y = (v[1] - mean) * rstd * gg[1] + bb[1];
    o0.z = (v[2] - mean) * rstd * gg[2] + bb[2];
    o0.w = (v[3] - mean) * rstd * gg[3] + bb[3];
    o1.x = (v[4] - mean) * rstd * gg[4] + bb[4];
    o1.y = (v[5] - mean) * rstd * gg[5] + bb[5];
    o1.z = (v[6] - mean) * rstd * gg[6] + bb[6];
    o1.w = (v[7] - mean) * rstd * gg[7] + bb[7];
    *reinterpret_cast<float4*>(&out[base])     = o0;
    *reinterpret_cast<float4*>(&out[base + 4]) = o1;
}

// ---------------------------------------------------------------------------
// Workspace layout (42.03 MB; all live ranges DISJOINT):
//   Qh  bf16 @ 0  .. 8 MB    (proj -> attn)
//   Kh  bf16 @ 8  .. 16 MB   (proj -> attn)
//   VhT bf16 @ 16 .. 24 MB   (proj -> attn)
//   Wt  bf16 @ 24 .. 26 MB   (transpose -> GEMMs)
//   Oa  bf16 @ 26 .. 34 MB   (attn -> ln1)
//   H1  bf16 @ 34 .. 42 MB   (ln1 -> ffn)
//   msentg f32 @ 42 MB (32 KB)
//   R2  bf16 @ 0 .. 8 MB     (ffn -> ln2)  [over DEAD Qh]
// d_out written only by LN2 (final).
// ---------------------------------------------------------------------------
extern "C" void kernel_launch(void* const* d_in, const int* in_sizes, int n_in,
                              void* d_out, int out_size, void* d_ws, size_t ws_size,
                              hipStream_t stream) {
    const float* Q     = (const float*)d_in[0];
    const float* K     = (const float*)d_in[1];
    const int*   maskp = (const int*)  d_in[2];
    const float* Wq    = (const float*)d_in[3];
    const float* bq    = (const float*)d_in[4];
    const float* Wk    = (const float*)d_in[5];
    const float* bk    = (const float*)d_in[6];
    const float* Wv    = (const float*)d_in[7];
    const float* bv    = (const float*)d_in[8];
    const float* Wo    = (const float*)d_in[9];
    const float* bo    = (const float*)d_in[10];
    const float* g0    = (const float*)d_in[11];
    const float* b0    = (const float*)d_in[12];
    const float* g1    = (const float*)d_in[13];
    const float* b1    = (const float*)d_in[14];

    float* out = (float*)d_out;
    char*  ws  = (char*)d_ws;
    __bf16* Qh     = (__bf16*)ws;
    __bf16* Kh     = (__bf16*)(ws + (8u  << 20));
    __bf16* VhT    = (__bf16*)(ws + (16u << 20));
    __bf16* Wt     = (__bf16*)(ws + (24u << 20));
    __bf16* Oa     = (__bf16*)(ws + (26u << 20));
    __bf16* H1     = (__bf16*)(ws + (34u << 20));
    float*  msentg = (float*)(ws + (42u << 20));
    __bf16* R2     = (__bf16*)ws;

    transpose_w_kernel<<<dim3(16, 16, 5), 256, 0, stream>>>(
        Wq, Wk, Wv, Wo, maskp, Wt, msentg);

    proj_mfma_kernel<<<dim3(768), 256, 0, stream>>>(
        Q, K, Wt, bq, bk, bv, Qh, Kh, VhT);

    attn_mfma_kernel<<<dim3(512), 256, 0, stream>>>(Qh, Kh, VhT, msentg, Oa);

    ln1_kernel<<<NROWS / 4, 256, 0, stream>>>(Oa, Q, g0, b0, H1);

    ffn_mfma_kernel<<<dim3(512), 256, 0, stream>>>(
        H1, Wt + (size_t)1536 * DIM, bo, R2);

    ln2_kernel<<<NROWS / 4, 256, 0, stream>>>(R2, g1, b1, out);
}

// Round 18
// 122.076 us; speedup vs baseline: 1.0578x; 1.0269x over previous
//
#include <hip/hip_runtime.h>
#include <math.h>

#define NB   4
#define SLQ  2048
#define SLK  2048
#define DIM  512
#define NH   8
#define HD   64          // head dim
#define NROWS (NB * SLQ) // 8192
#define NT   (SLK / 64)  // 32 KV tiles

typedef __attribute__((ext_vector_type(8)))  __bf16 bf16x8;
typedef __attribute__((ext_vector_type(4)))  __bf16 bf16x4;
typedef __attribute__((ext_vector_type(2)))  __bf16 bf16x2;
typedef __attribute__((ext_vector_type(4)))  float  f32x4;
typedef __attribute__((ext_vector_type(16))) float  f32x16;
typedef __attribute__((ext_vector_type(4)))  unsigned int u32x4;

// async global->LDS, 16B per lane: dest = lds_base + lane*16 (HW-defined)
typedef const __attribute__((address_space(1))) void* as1_cptr;
typedef __attribute__((address_space(3))) void*       as3_ptr;
__device__ __forceinline__ void async_ld16(const void* g, void* s) {
    __builtin_amdgcn_global_load_lds((as1_cptr)g, (as3_ptr)s, 16, 0, 0);
}

// ---------------------------------------------------------------------------
// Weight transpose + fp32->bf16: Wt[512*m + n][k] = W_m[k][n]  (m = 0..3)
// z-slice m==4: msentg[b*SLK + k] = pad_mask ? 0 : -1e30 (fp32)
// ---------------------------------------------------------------------------
__global__ __launch_bounds__(256)
void transpose_w_kernel(const float* __restrict__ Wq, const float* __restrict__ Wk,
                        const float* __restrict__ Wv, const float* __restrict__ Wo,
                        const int* __restrict__ maskp,
                        __bf16* __restrict__ Wt, float* __restrict__ msentg) {
    const int m = blockIdx.z;
    const int t = threadIdx.x;
    if (m == 4) {
        const int idx = (blockIdx.y * 16 + blockIdx.x) * 256 + t;
        if (idx < NB * SLK) msentg[idx] = maskp[idx] ? 0.f : -1e30f;
        return;
    }
    __shared__ float Ls[32][33];
    const float* W = (m == 0) ? Wq : (m == 1) ? Wk : (m == 2) ? Wv : Wo;
    const int k0 = blockIdx.y * 32, n0 = blockIdx.x * 32;
    const int r  = t >> 3, c = (t & 7) * 4;

    const float4 v = *reinterpret_cast<const float4*>(&W[(size_t)(k0 + r) * DIM + n0 + c]);
    Ls[r][c + 0] = v.x; Ls[r][c + 1] = v.y; Ls[r][c + 2] = v.z; Ls[r][c + 3] = v.w;
    __syncthreads();

    const int n = t >> 3, k = (t & 7) * 4;
    bf16x4 o;
    o[0] = (__bf16)Ls[k + 0][n];
    o[1] = (__bf16)Ls[k + 1][n];
    o[2] = (__bf16)Ls[k + 2][n];
    o[3] = (__bf16)Ls[k + 3][n];
    *reinterpret_cast<bf16x4*>(&Wt[(size_t)(512 * m + n0 + n) * DIM + k0 + k]) = o;
}

// ---------------------------------------------------------------------------
// Fused projection GEMM, BN=128, pipelined, XCD-chunked swizzle
// (byte-identical to round 15).
// ---------------------------------------------------------------------------
__global__ __launch_bounds__(256)
void proj_mfma_kernel(const float* __restrict__ Qp, const float* __restrict__ Kp,
                      const __bf16* __restrict__ Wt,
                      const float* __restrict__ bq, const float* __restrict__ bk,
                      const float* __restrict__ bv,
                      __bf16* __restrict__ Qh, __bf16* __restrict__ Kh,
                      __bf16* __restrict__ VhT) {
    __shared__ __bf16 As[2][128][64];
    __shared__ __bf16 Bs[2][128][64];

    const int pos  = blockIdx.x;
    const int orig = (pos & 7) * 96 + (pos >> 3);   // 768 = 8*96: bijective
    const int by   = orig / 12;
    const int bx   = orig % 12;
    const int mode = bx >> 2;        // 0 Q / 1 K / 2 V
    const int cb   = bx & 3;
    const float*  Ag = (mode == 0) ? Qp : Kp;
    const __bf16* Bt = Wt + (size_t)(mode * 512) * DIM;
    const float*  biasp = ((mode == 0) ? bq : (mode == 1) ? bk : bv) + cb * 128;
    const int col0 = cb * 128;

    const int t  = threadIdx.x;
    const int w  = t >> 6, l = t & 63, lg = l >> 4, lc = l & 15;
    const int wr = w >> 1, wc = w & 1;
    const int row0 = by * 128;

    float biasr[4];
    #pragma unroll
    for (int nj = 0; nj < 4; ++nj) biasr[nj] = biasp[wc * 64 + nj * 16 + lc];
    asm volatile("s_waitcnt vmcnt(0)" ::: "memory");

    const int sr   = t >> 3;
    const int sc8  = t & 7;
    const int swA  = (sc8 ^ (sr & 7)) * 8;
    const int srow = l >> 3;
    const int schk = (l & 7) ^ srow;
    const int x7   = lc & 7;

    f32x4 acc[4][4];
    #pragma unroll
    for (int mi = 0; mi < 4; ++mi)
        #pragma unroll
        for (int nj = 0; nj < 4; ++nj) acc[mi][nj] = f32x4{0.f, 0.f, 0.f, 0.f};

    float4 areg[4][2];

#define PROJ_CF asm volatile("" ::: "memory")
#define PROJ_ISSUE_A(k0_) { _Pragma("unroll") for (int i = 0; i < 4; ++i) {    \
        const float* ap = Ag + (size_t)(row0 + i * 32 + sr) * DIM + (k0_) + sc8 * 8; \
        areg[i][0] = *reinterpret_cast<const float4*>(ap);                     \
        areg[i][1] = *reinterpret_cast<const float4*>(ap + 4); } PROJ_CF; }
#define PROJ_CVT(nb_) { _Pragma("unroll") for (int i = 0; i < 4; ++i) {        \
        bf16x8 hv;                                                             \
        hv[0] = (__bf16)areg[i][0].x; hv[1] = (__bf16)areg[i][0].y;            \
        hv[2] = (__bf16)areg[i][0].z; hv[3] = (__bf16)areg[i][0].w;            \
        hv[4] = (__bf16)areg[i][1].x; hv[5] = (__bf16)areg[i][1].y;            \
        hv[6] = (__bf16)areg[i][1].z; hv[7] = (__bf16)areg[i][1].w;            \
        *reinterpret_cast<bf16x8*>(&As[nb_][i * 32 + sr][swA]) = hv; } }
#define PROJ_STAGE_B(nb_, k0_) { _Pragma("unroll") for (int i = 0; i < 4; ++i) { \
        const int rb = w * 32 + i * 8;                                         \
        async_ld16(Bt + (size_t)(col0 + rb + srow) * DIM + (k0_) + schk * 8,   \
                   &Bs[nb_][rb][0]); } PROJ_CF; }

    PROJ_ISSUE_A(0);
    asm volatile("s_waitcnt vmcnt(0)" ::: "memory");
    PROJ_CVT(0);
    PROJ_STAGE_B(0, 0);
    PROJ_ISSUE_A(64);
    asm volatile("s_waitcnt vmcnt(8)" ::: "memory");
    asm volatile("s_waitcnt lgkmcnt(0)" ::: "memory");
    __builtin_amdgcn_s_barrier();

    for (int kt = 0; kt < 8; ++kt) {
        const int cur = kt & 1;
        if (kt + 1 < 8) PROJ_STAGE_B((kt + 1) & 1, (kt + 1) * 64);

        #pragma unroll
        for (int ks = 0; ks < 2; ++ks) {
            bf16x8 af[4], bfv[4];
            #pragma unroll
            for (int mi = 0; mi < 4; ++mi)
                af[mi] = *reinterpret_cast<const bf16x8*>(
                    &As[cur][wr * 64 + mi * 16 + lc][((ks * 4 + lg) ^ x7) << 3]);
            #pragma unroll
            for (int nj = 0; nj < 4; ++nj)
                bfv[nj] = *reinterpret_cast<const bf16x8*>(
                    &Bs[cur][wc * 64 + nj * 16 + lc][((ks * 4 + lg) ^ x7) << 3]);
            #pragma unroll
            for (int mi = 0; mi < 4; ++mi)
                #pragma unroll
                for (int nj = 0; nj < 4; ++nj)
                    acc[mi][nj] = __builtin_amdgcn_mfma_f32_16x16x32_bf16(
                        af[mi], bfv[nj], acc[mi][nj], 0, 0, 0);
        }

        if (kt + 1 < 8) {
            asm volatile("s_waitcnt vmcnt(4)" ::: "memory");
            PROJ_CVT((kt + 1) & 1);
            if (kt + 2 < 8) {
                PROJ_ISSUE_A((kt + 2) * 64);
                asm volatile("s_waitcnt vmcnt(8)" ::: "memory");
            } else {
                asm volatile("s_waitcnt vmcnt(0)" ::: "memory");
            }
            asm volatile("s_waitcnt lgkmcnt(0)" ::: "memory");
            __builtin_amdgcn_s_barrier();
        }
    }

    #pragma unroll
    for (int mi = 0; mi < 4; ++mi) {
        #pragma unroll
        for (int nj = 0; nj < 4; ++nj) {
            const int cl  = wc * 64 + nj * 16 + lc;
            const float bb = biasr[nj];
            if (mode == 2) {
                const int dcol = col0 + cl;
                const int hh = dcol >> 6, dd = dcol & 63;
                const int row = row0 + wr * 64 + mi * 16 + lg * 4;
                const int bi  = row >> 11, key = row & 2047;
                bf16x4 pk;
                #pragma unroll
                for (int r = 0; r < 4; ++r) pk[r] = (__bf16)(acc[mi][nj][r] + bb);
                *reinterpret_cast<bf16x4*>(
                    &VhT[((size_t)(bi * NH + hh) * HD + dd) * SLK + key]) = pk;
            } else {
                __bf16* out = (mode == 0) ? Qh : Kh;
                #pragma unroll
                for (int r = 0; r < 4; ++r) {
                    const int row = row0 + wr * 64 + mi * 16 + lg * 4 + r;
                    out[(size_t)row * DIM + col0 + cl] = (__bf16)(acc[mi][nj][r] + bb);
                }
            }
        }
    }
}

// ---------------------------------------------------------------------------
// FFN GEMM (byte-identical to round 15).
// ---------------------------------------------------------------------------
__global__ __launch_bounds__(256)
void ffn_mfma_kernel(const __bf16* __restrict__ A, const __bf16* __restrict__ Bt,
                     const float* __restrict__ bias, __bf16* __restrict__ outv) {
    __shared__ __bf16 As[128][72];
    __shared__ __bf16 Bs[64][72];

    const int pos  = blockIdx.x;
    const int orig = (pos & 7) * 64 + (pos >> 3);   // 512 = 8*64: bijective
    const int by   = orig >> 3;
    const int bxc  = orig & 7;

    const int t  = threadIdx.x;
    const int w  = t >> 6, l = t & 63, lg = l >> 4, lc = l & 15;
    const int wr = w >> 1, wc = w & 1;
    const int row0 = by * 128, col0 = bxc * 64;

    f32x4 acc[4][2];
    #pragma unroll
    for (int mi = 0; mi < 4; ++mi)
        #pragma unroll
        for (int nj = 0; nj < 2; ++nj) acc[mi][nj] = f32x4{0.f, 0.f, 0.f, 0.f};

    const int sr = t >> 3, sc = (t & 7) * 8;

    for (int k0 = 0; k0 < DIM; k0 += 64) {
        __syncthreads();
        #pragma unroll
        for (int i = 0; i < 4; ++i) {
            const int r = i * 32 + sr;
            *reinterpret_cast<bf16x8*>(&As[r][sc]) =
                *reinterpret_cast<const bf16x8*>(&A[(size_t)(row0 + r) * DIM + k0 + sc]);
        }
        #pragma unroll
        for (int i = 0; i < 2; ++i) {
            const int n = i * 32 + sr;
            *reinterpret_cast<bf16x8*>(&Bs[n][sc]) =
                *reinterpret_cast<const bf16x8*>(&Bt[(size_t)(col0 + n) * DIM + k0 + sc]);
        }
        __syncthreads();

        #pragma unroll
        for (int ks = 0; ks < 2; ++ks) {
            bf16x8 af[4], bfv[2];
            #pragma unroll
            for (int mi = 0; mi < 4; ++mi)
                af[mi] = *reinterpret_cast<const bf16x8*>(
                    &As[wr * 64 + mi * 16 + lc][ks * 32 + lg * 8]);
            #pragma unroll
            for (int nj = 0; nj < 2; ++nj)
                bfv[nj] = *reinterpret_cast<const bf16x8*>(
                    &Bs[wc * 32 + nj * 16 + lc][ks * 32 + lg * 8]);
            #pragma unroll
            for (int mi = 0; mi < 4; ++mi)
                #pragma unroll
                for (int nj = 0; nj < 2; ++nj)
                    acc[mi][nj] = __builtin_amdgcn_mfma_f32_16x16x32_bf16(
                        af[mi], bfv[nj], acc[mi][nj], 0, 0, 0);
        }
    }

    #pragma unroll
    for (int mi = 0; mi < 4; ++mi) {
        #pragma unroll
        for (int nj = 0; nj < 2; ++nj) {
            const int cl  = wc * 32 + nj * 16 + lc;
            const int col = col0 + cl;
            #pragma unroll
            for (int r = 0; r < 4; ++r) {
                const int row = row0 + wr * 64 + mi * 16 + lg * 4 + r;
                const float vv = acc[mi][nj][r] + bias[col];
                outv[(size_t)row * DIM + col] =
                    (__bf16)((float)A[(size_t)row * DIM + col] + fmaxf(vv, 0.f));
            }
        }
    }
}

// ---------------------------------------------------------------------------
// bf16 MFMA flash attention — round-15 3-buffer schedule, with two
// VALU->MFMA offloads:
// (1) QK^T's first MFMA takes a hoisted zero f32x16 as C (no per-tile
//     32x v_mov zero-init of sacc).
// (2) l computed on the matrix pipe: lacc = mfma(pfrag, ones_bf16, lacc).
//     With B = all-ones every output column holds the P row-sum, and the
//     32x32 C-layout makes lacc[4m+j] = l[q-row qr] in exactly the same
//     register slots as oacc -> per-element normalize, NO cross-lane
//     broadcast in the epilogue.
// ---------------------------------------------------------------------------
__global__ __launch_bounds__(256)
void attn_mfma_kernel(const __bf16* __restrict__ Qh, const __bf16* __restrict__ Kh,
                      const __bf16* __restrict__ VhT, const float* __restrict__ msentg,
                      __bf16* __restrict__ Oa) {
    const int pos  = blockIdx.x;
    const int orig = (pos & 7) * 64 + (pos >> 3);   // 512 % 8 == 0: bijective
    const int qb = orig & 15;          // 16 q-tiles of 128 rows
    const int h  = (orig >> 4) & 7;
    const int b  = orig >> 7;

    const int tid = threadIdx.x;
    const int w   = tid >> 6;
    const int l   = tid & 63;
    const int ql  = l & 31;
    const int hi  = l >> 5;
    const int x7  = ql & 7;

    __shared__ __bf16 Ks[3][64][64];   // [key][d], swizzled content
    __shared__ __bf16 Vt[3][64][64];   // [d][key], swizzled content
    __shared__ float  msent[SLK];      // additive sentinels (8 KB)

    {
        const float* mb = msentg + b * SLK;
        #pragma unroll
        for (int i = 0; i < 2; ++i) {
            const int idx = (i * 256 + tid) * 4;
            *reinterpret_cast<f32x4*>(&msent[idx]) =
                *reinterpret_cast<const f32x4*>(&mb[idx]);
        }
    }

    const int q0 = qb * 128 + w * 32;  // wave's 32 q rows
    bf16x8 qf[4];
    {
        const __bf16* qrow = Qh + (size_t)(b * SLQ + q0 + ql) * DIM + h * HD + hi * 8;
        #pragma unroll
        for (int c = 0; c < 4; ++c)
            qf[c] = *reinterpret_cast<const bf16x8*>(qrow + c * 16);
    }

    const __bf16* kbase = Kh  + (size_t)b * SLK * DIM + h * HD;
    const __bf16* vbase = VhT + (size_t)(b * NH + h) * HD * SLK;

    const int srow = l >> 3;
    const int schk = (l & 7) ^ srow;

    auto STAGE = [&](int nb_, int k0_) {
        #pragma unroll
        for (int i = 0; i < 2; ++i) {
            const int rb = w * 16 + i * 8;   // wave-uniform, multiple of 8
            async_ld16(kbase + (size_t)(k0_ + rb + srow) * DIM + schk * 8,
                       &Ks[nb_][rb][0]);
            async_ld16(vbase + (size_t)(rb + srow) * SLK + k0_ + schk * 8,
                       &Vt[nb_][rb][0]);
        }
    };

    // hoisted constants: zero C for QK^T, ones B for the l-MFMA
    f32x16 zf;
    #pragma unroll
    for (int i = 0; i < 16; ++i) zf[i] = 0.f;
    bf16x8 onesb;
    #pragma unroll
    for (int i = 0; i < 8; ++i) onesb[i] = (__bf16)1.0f;

    f32x16 oacc[2], lacc;
    #pragma unroll
    for (int i = 0; i < 16; ++i) { oacc[0][i] = 0.f; oacc[1][i] = 0.f; lacc[i] = 0.f; }
    const float scale2 = 0.06377551f;          // (1/sqrt(512)) * log2(e)

    STAGE(0, 0);
    STAGE(1, 64);
    asm volatile("s_waitcnt lgkmcnt(0)" ::: "memory");   // own msent writes done

    int rd = 0;
    for (int t = 0; t < NT; ++t) {
        if (t == NT - 1) asm volatile("s_waitcnt vmcnt(0)" ::: "memory");
        else             asm volatile("s_waitcnt vmcnt(4)" ::: "memory");
        __builtin_amdgcn_s_barrier();    // RAW barrier: no implicit drain

        if (t + 2 < NT) {
            const int st = (rd + 2 >= 3) ? rd - 1 : rd + 2;   // (rd+2)%3
            STAGE(st, (t + 2) * 64);
        }

        const int k0 = t * 64;
        const __bf16* KsC = &Ks[rd][0][0];
        const __bf16* VtC = &Vt[rd][0][0];

        // ---- S^T = K . Q^T  (8 MFMAs; first of each chain takes zero-C) ----
        f32x16 sacc[2];
        __builtin_amdgcn_s_setprio(1);
        #pragma unroll
        for (int kb = 0; kb < 2; ++kb) {
            #pragma unroll
            for (int c = 0; c < 4; ++c) {
                const bf16x8 kf = *reinterpret_cast<const bf16x8*>(
                    &KsC[(kb * 32 + ql) * 64 + (((2 * c + hi) ^ x7) << 3)]);
                sacc[kb] = __builtin_amdgcn_mfma_f32_32x32x16_bf16(
                    kf, qf[c], (c == 0) ? zf : sacc[kb], 0, 0, 0);
            }
        }
        __builtin_amdgcn_s_setprio(0);

        // ---- fixed-shift softmax + pack to bf16 pairs (no l adds) ----
        unsigned int P2[2][8];
        #pragma unroll
        for (int kb = 0; kb < 2; ++kb) {
            #pragma unroll
            for (int m = 0; m < 4; ++m) {
                const f32x4 tm = *reinterpret_cast<const f32x4*>(
                    &msent[k0 + kb * 32 + 8 * m + 4 * hi]);
                float p[4];
                #pragma unroll
                for (int j = 0; j < 4; ++j)
                    p[j] = __builtin_amdgcn_exp2f(
                        fmaf(sacc[kb][4 * m + j], scale2, tm[j]));  // masked -> 0
                bf16x2 w0, w1;
                w0[0] = (__bf16)p[0]; w0[1] = (__bf16)p[1];
                w1[0] = (__bf16)p[2]; w1[1] = (__bf16)p[3];
                P2[kb][2 * m]     = __builtin_bit_cast(unsigned int, w0);
                P2[kb][2 * m + 1] = __builtin_bit_cast(unsigned int, w1);
            }
        }

        // ---- permlane32_swap: build PV A-frags in place ----
        #pragma unroll
        for (int kb = 0; kb < 2; ++kb) {
            #pragma unroll
            for (int cc = 0; cc < 2; ++cc) {
                asm volatile("v_permlane32_swap_b32 %0, %1"
                             : "+v"(P2[kb][4 * cc + 0]), "+v"(P2[kb][4 * cc + 2]));
                asm volatile("v_permlane32_swap_b32 %0, %1"
                             : "+v"(P2[kb][4 * cc + 1]), "+v"(P2[kb][4 * cc + 3]));
            }
        }
        bf16x8 pfrag[4];
        #pragma unroll
        for (int c = 0; c < 4; ++c) {
            const int kb = c >> 1, cc = c & 1;
            u32x4 fw;
            fw.x = P2[kb][4 * cc + 0]; fw.y = P2[kb][4 * cc + 1];
            fw.z = P2[kb][4 * cc + 2]; fw.w = P2[kb][4 * cc + 3];
            pfrag[c] = __builtin_bit_cast(bf16x8, fw);
        }

        // ---- O += P . V  (8 MFMAs) + l += P . 1  (4 MFMAs, idle pipe) ----
        __builtin_amdgcn_s_setprio(1);
        #pragma unroll
        for (int c = 0; c < 4; ++c)
            lacc = __builtin_amdgcn_mfma_f32_32x32x16_bf16(
                pfrag[c], onesb, lacc, 0, 0, 0);
        #pragma unroll
        for (int db = 0; db < 2; ++db) {
            #pragma unroll
            for (int c = 0; c < 4; ++c) {
                const bf16x8 vf = *reinterpret_cast<const bf16x8*>(
                    &VtC[(db * 32 + ql) * 64 + (((2 * c + hi) ^ x7) << 3)]);
                oacc[db] = __builtin_amdgcn_mfma_f32_32x32x16_bf16(
                    pfrag[c], vf, oacc[db], 0, 0, 0);
            }
        }
        __builtin_amdgcn_s_setprio(0);

        rd = (rd == 2) ? 0 : rd + 1;
    }

    // ---- epilogue: per-element normalize (lacc slots match oacc slots) ----
    #pragma unroll
    for (int db = 0; db < 2; ++db) {
        #pragma unroll
        for (int m = 0; m < 4; ++m) {
            #pragma unroll
            for (int j = 0; j < 4; ++j) {
                const int qr = 8 * m + 4 * hi + j;
                const float lq  = lacc[4 * m + j];
                const float inv = (lq > 0.f) ? 1.f / lq : 0.f;  // all-masked -> 0
                Oa[(size_t)(b * SLQ + q0 + qr) * DIM + h * HD + db * 32 + ql] =
                    (__bf16)(oacc[db][4 * m + j] * inv);
            }
        }
    }
}

// ---------------------------------------------------------------------------
// Wave helper + LayerNorms (round-15 versions)
// ---------------------------------------------------------------------------
__device__ __forceinline__ float wave_sum(float v) {
    #pragma unroll
    for (int off = 32; off > 0; off >>= 1) v += __shfl_xor(v, off, 64);
    return v;
}

// LN1: out(bf16) = LN( X(bf16 attn out) + Y(fp32 residual) )
__global__ __launch_bounds__(256)
void ln1_kernel(const __bf16* X, const float* Y,
                const float* g, const float* bta, __bf16* out) {
    const int w    = threadIdx.x >> 6;
    const int lane = threadIdx.x & 63;
    const int row  = blockIdx.x * 4 + w;
    const size_t base = (size_t)row * DIM + lane * 8;

    const bf16x8 xv = *reinterpret_cast<const bf16x8*>(&X[base]);
    const float4 y0 = *reinterpret_cast<const float4*>(&Y[base]);
    const float4 y1 = *reinterpret_cast<const float4*>(&Y[base + 4]);
    float v[8];
    v[0] = (float)xv[0] + y0.x; v[1] = (float)xv[1] + y0.y;
    v[2] = (float)xv[2] + y0.z; v[3] = (float)xv[3] + y0.w;
    v[4] = (float)xv[4] + y1.x; v[5] = (float)xv[5] + y1.y;
    v[6] = (float)xv[6] + y1.z; v[7] = (float)xv[7] + y1.w;

    float s = 0.f, ss = 0.f;
    #pragma unroll
    for (int i = 0; i < 8; ++i) { s += v[i]; ss += v[i] * v[i]; }
    s  = wave_sum(s);
    ss = wave_sum(ss);
    const float mean = s * (1.f / DIM);
    const float var  = ss * (1.f / DIM) - mean * mean;
    const float rstd = rsqrtf(var + 1e-5f);

    const float4 g0 = *reinterpret_cast<const float4*>(&g[lane * 8]);
    const float4 g1 = *reinterpret_cast<const float4*>(&g[lane * 8 + 4]);
    const float4 b0 = *reinterpret_cast<const float4*>(&bta[lane * 8]);
    const float4 b1 = *reinterpret_cast<const float4*>(&bta[lane * 8 + 4]);
    float gg[8] = {g0.x, g0.y, g0.z, g0.w, g1.x, g1.y, g1.z, g1.w};
    float bb[8] = {b0.x, b0.y, b0.z, b0.w, b1.x, b1.y, b1.z, b1.w};

    bf16x8 o;
    #pragma unroll
    for (int i = 0; i < 8; ++i)
        o[i] = (__bf16)((v[i] - mean) * rstd * gg[i] + bb[i]);
    *reinterpret_cast<bf16x8*>(&out[base]) = o;
}

// LN2: out(fp32) = LN( X(bf16) )
__global__ __launch_bounds__(256)
void ln2_kernel(const __bf16* X, const float* g, const float* bta, float* out) {
    const int w    = threadIdx.x >> 6;
    const int lane = threadIdx.x & 63;
    const int row  = blockIdx.x * 4 + w;
    const size_t base = (size_t)row * DIM + lane * 8;

    const bf16x8 xv = *reinterpret_cast<const bf16x8*>(&X[base]);
    float v[8];
    #pragma unroll
    for (int i = 0; i < 8; ++i) v[i] = (float)xv[i];

    float s = 0.f, ss = 0.f;
    #pragma unroll
    for (int i = 0; i < 8; ++i) { s += v[i]; ss += v[i] * v[i]; }
    s  = wave_sum(s);
    ss = wave_sum(ss);
    const float mean = s * (1.f / DIM);
    const float var  = ss * (1.f / DIM) - mean * mean;
    const float rstd = rsqrtf(var + 1e-5f);

    const float4 g0 = *reinterpret_cast<const float4*>(&g[lane * 8]);
    const float4 g1 = *reinterpret_cast<const float4*>(&g[lane * 8 + 4]);
    const float4 b0 = *reinterpret_cast<const float4*>(&bta[lane * 8]);
    const float4 b1 = *reinterpret_cast<const float4*>(&bta[lane * 8 + 4]);
    float gg[8] = {g0.x, g0.y, g0.z, g0.w, g1.x, g1.y, g1.z, g1.w};
    float bb[8] = {b0.x, b0.y, b0.z, b0.w, b1.x, b1.y, b1.z, b1.w};

    float4 o0, o1;
    o0.x = (v[0] - mean) * rstd * gg[0] + bb[0];
    o0.y = (v[1] - mean) * rstd * gg[1] + bb[1];
    o0.z = (v[2] - mean) * rstd * gg[2] + bb[2];
    o0.w = (v[3] - mean) * rstd * gg[3] + bb[3];
    o1.x = (v[4] - mean) * rstd * gg[4] + bb[4];
    o1.y = (v[5] - mean) * rstd * gg[5] + bb[5];
    o1.z = (v[6] - mean) * rstd * gg[6] + bb[6];
    o1.w = (v[7] - mean) * rstd * gg[7] + bb[7];
    *reinterpret_cast<float4*>(&out[base])     = o0;
    *reinterpret_cast<float4*>(&out[base + 4]) = o1;
}

// ---------------------------------------------------------------------------
// Workspace layout (42.03 MB; all live ranges DISJOINT):
//   Qh  bf16 @ 0  .. 8 MB    (proj -> attn)
//   Kh  bf16 @ 8  .. 16 MB   (proj -> attn)
//   VhT bf16 @ 16 .. 24 MB   (proj -> attn)
//   Wt  bf16 @ 24 .. 26 MB   (transpose -> GEMMs)
//   Oa  bf16 @ 26 .. 34 MB   (attn -> ln1)
//   H1  bf16 @ 34 .. 42 MB   (ln1 -> ffn)
//   msentg f32 @ 42 MB (32 KB)
//   R2  bf16 @ 0 .. 8 MB     (ffn -> ln2)  [over DEAD Qh]
// d_out written only by LN2 (final).
// ---------------------------------------------------------------------------
extern "C" void kernel_launch(void* const* d_in, const int* in_sizes, int n_in,
                              void* d_out, int out_size, void* d_ws, size_t ws_size,
                              hipStream_t stream) {
    const float* Q     = (const float*)d_in[0];
    const float* K     = (const float*)d_in[1];
    const int*   maskp = (const int*)  d_in[2];
    const float* Wq    = (const float*)d_in[3];
    const float* bq    = (const float*)d_in[4];
    const float* Wk    = (const float*)d_in[5];
    const float* bk    = (const float*)d_in[6];
    const float* Wv    = (const float*)d_in[7];
    const float* bv    = (const float*)d_in[8];
    const float* Wo    = (const float*)d_in[9];
    const float* bo    = (const float*)d_in[10];
    const float* g0    = (const float*)d_in[11];
    const float* b0    = (const float*)d_in[12];
    const float* g1    = (const float*)d_in[13];
    const float* b1    = (const float*)d_in[14];

    float* out = (float*)d_out;
    char*  ws  = (char*)d_ws;
    __bf16* Qh     = (__bf16*)ws;
    __bf16* Kh     = (__bf16*)(ws + (8u  << 20));
    __bf16* VhT    = (__bf16*)(ws + (16u << 20));
    __bf16* Wt     = (__bf16*)(ws + (24u << 20));
    __bf16* Oa     = (__bf16*)(ws + (26u << 20));
    __bf16* H1     = (__bf16*)(ws + (34u << 20));
    float*  msentg = (float*)(ws + (42u << 20));
    __bf16* R2     = (__bf16*)ws;

    transpose_w_kernel<<<dim3(16, 16, 5), 256, 0, stream>>>(
        Wq, Wk, Wv, Wo, maskp, Wt, msentg);

    proj_mfma_kernel<<<dim3(768), 256, 0, stream>>>(
        Q, K, Wt, bq, bk, bv, Qh, Kh, VhT);

    attn_mfma_kernel<<<dim3(512), 256, 0, stream>>>(Qh, Kh, VhT, msentg, Oa);

    ln1_kernel<<<NROWS / 4, 256, 0, stream>>>(Oa, Q, g0, b0, H1);

    ffn_mfma_kernel<<<dim3(512), 256, 0, stream>>>(
        H1, Wt + (size_t)1536 * DIM, bo, R2);

    ln2_kernel<<<NROWS / 4, 256, 0, stream>>>(R2, g1, b1, out);
}